// Round 5
// baseline (319.337 us; speedup 1.0000x reference)
//
#include <hip/hip_runtime.h>
#include <stdint.h>

#define N_NODES 100000
#define N_FEAT 128
#define N_EDGES 3200000
#define SLICE_U 800000            // uints per slice region (100000 rows x 8 uints)

// ---------- bf16 helpers ----------
static __device__ __forceinline__ unsigned int f2bf_u(float f) {
    unsigned int u = __float_as_uint(f);
    u += 0x7FFFu + ((u >> 16) & 1u);   // RNE
    return u >> 16;
}

typedef __bf16 bf16x8 __attribute__((ext_vector_type(8)));
typedef float f32x4 __attribute__((ext_vector_type(4)));

// ---------- Kernel 1 (prep): CSR row_ptr + filters -> bf16 fragment-linear ----------
// blocks [0,12500):      CSR row_ptr scatter from sorted edge_dst
// blocks [12500,12564):  filters -> bf16 in MFMA B-fragment-linear order:
//   flat short index i holds F[k][n] with n = (i>>11)*16 + ((i>>3)&15),
//   k = ((i>>9)&3)*32 + ((i>>7)&3)*8 + (i&7)
__global__ __launch_bounds__(256) void k_prep(
        const float* __restrict__ f, unsigned short* __restrict__ fB,
        const int* __restrict__ dst, int* __restrict__ row_ptr) {
    int b = blockIdx.x;
    if (b < 12500) {
        int e = b * 256 + threadIdx.x;
        if (e >= N_EDGES) return;
        int dcur = dst[e];
        if (e == 0) {
            for (int d = 0; d <= dcur; ++d) row_ptr[d] = 0;
        } else {
            int dprev = dst[e - 1];
            for (int d = dprev + 1; d <= dcur; ++d) row_ptr[d] = e;
        }
        if (e == N_EDGES - 1) {
            for (int d = dcur + 1; d <= N_NODES; ++d) row_ptr[d] = N_EDGES;
        }
    } else {
        int i = (b - 12500) * 256 + threadIdx.x;   // flat fragment-linear index
        if (i >= N_FEAT * N_FEAT) return;
        int n = ((i >> 11) << 4) | ((i >> 3) & 15);
        int k = (((i >> 9) & 3) << 5) | (((i >> 7) & 3) << 3) | (i & 7);
        fB[i] = (unsigned short)f2bf_u(f[k * 128 + n]);
    }
}

// ---------- Kernel 2: XF = x @ F (MFMA), fused biased-uint8 row quantization ----------
// Block 256 (4 waves), 64 rows/block. B in LDS fragment-linear (32KB, 5 blocks/CU).
// xi8 layout is SLICE-MAJOR: region s (s=c>>3) holds each row's uints [8s,8s+8)
// contiguously (32 B/row) so one slice's gather working set is 3.2 MB (fits XCD L2).
// Within a uint c: byte b = feature 32*b + c.
__global__ __launch_bounds__(256) void k_xf(
        const float* __restrict__ x,
        const unsigned short* __restrict__ fB,
        unsigned int* __restrict__ xi8,          // 4 x [N][8] uints, slice-major
        float* __restrict__ xscale) {            // [N]
    __shared__ unsigned short Bbuf[16384];       // 32768 B exactly
    int t = threadIdx.x;
    for (int i = 0; i < 8; ++i)
        ((uint4*)Bbuf)[t + i * 256] = ((const uint4*)fB)[t + i * 256];
    __syncthreads();

    int wave = t >> 6, lane = t & 63, m15 = lane & 15, q = lane >> 4;
    int row = blockIdx.x * 64 + wave * 16 + m15;
    int rowc = min(row, N_NODES - 1);            // clamp loads; stores guarded

    f32x4 acc[8];
#pragma unroll
    for (int j = 0; j < 8; ++j) acc[j] = f32x4{0.f, 0.f, 0.f, 0.f};

#pragma unroll
    for (int kkidx = 0; kkidx < 4; ++kkidx) {
        const float* ap = x + (size_t)rowc * 128 + kkidx * 32 + q * 8;
        float4 v0 = *(const float4*)ap;
        float4 v1 = *(const float4*)(ap + 4);
        union { bf16x8 v; unsigned short s[8]; } au;
        au.s[0] = (unsigned short)f2bf_u(v0.x);
        au.s[1] = (unsigned short)f2bf_u(v0.y);
        au.s[2] = (unsigned short)f2bf_u(v0.z);
        au.s[3] = (unsigned short)f2bf_u(v0.w);
        au.s[4] = (unsigned short)f2bf_u(v1.x);
        au.s[5] = (unsigned short)f2bf_u(v1.y);
        au.s[6] = (unsigned short)f2bf_u(v1.z);
        au.s[7] = (unsigned short)f2bf_u(v1.w);
#pragma unroll
        for (int j = 0; j < 8; ++j) {
            bf16x8 bfrag = *(const bf16x8*)(Bbuf + (((j * 4 + kkidx) * 64 + lane) * 8));
            acc[j] = __builtin_amdgcn_mfma_f32_16x16x32_bf16(au.v, bfrag, acc[j], 0, 0, 0);
        }
    }

    int rowbase = blockIdx.x * 64 + wave * 16 + q * 4;   // D: row=q*4+r, col=j*16+m15
#pragma unroll
    for (int r = 0; r < 4; ++r) {
        float mx = 0.f;
#pragma unroll
        for (int j = 0; j < 8; ++j) mx = fmaxf(mx, fabsf(acc[j][r]));
        for (int d = 1; d < 16; d <<= 1) mx = fmaxf(mx, __shfl_xor(mx, d));
        float inv = 127.f / fmaxf(mx, 1e-20f);
        unsigned int u0 = 0, u1 = 0;
#pragma unroll
        for (int bb = 0; bb < 4; ++bb) {
            unsigned int q0 = (unsigned int)(int)(rintf(acc[2 * bb][r] * inv) + 128.f);
            unsigned int q1 = (unsigned int)(int)(rintf(acc[2 * bb + 1][r] * inv) + 128.f);
            u0 |= (q0 & 0xFFu) << (8 * bb);
            u1 |= (q1 & 0xFFu) << (8 * bb);
        }
        int gr = rowbase + r;
        if (gr < N_NODES) {
            int s0 = m15 >> 3, p0 = m15 & 7;
            xi8[s0 * SLICE_U + gr * 8 + p0] = u0;             // uint c = m15
            xi8[(2 + s0) * SLICE_U + gr * 8 + p0] = u1;       // uint c = 16+m15
            if (m15 == 0) xscale[gr] = mx * (1.f / 127.f);
        }
    }
}

// ---------- Kernel 3: feature-sliced aggregation, fp32 out direct ----------
// Grid = 25000 node-groups x 4 slices; slice = blockIdx & 3 so the empirical
// round-robin bid->XCD map (%8) pins one 3.2 MB slice per XCD L2.
// Wave = one node-slice task. Lane = (group g8 = lane>>3, uint l8 = lane&7):
// per j-step group g8 gathers edge (j*8+g8)'s 32B row-slice, lane reads uint l8.
// Meta/out use nontemporal to keep the gather table L2-resident.
// -128 bias via aw (sum of folded weights) accumulated at staging -- exact.
__global__ __launch_bounds__(256) void k_aggregate(
        const unsigned int* __restrict__ xi8,    // slice-major table
        const float* __restrict__ xscale,        // [N]
        const int* __restrict__ src,
        const float* __restrict__ w,
        const int* __restrict__ row_ptr,
        float* __restrict__ out) {               // [N][128] fp32 (final output)
    __shared__ uint2 smeta[4][64];
    int wave = threadIdx.x >> 6, lane = threadIdx.x & 63;
    int s = blockIdx.x & 3;
    int node = (blockIdx.x >> 2) * 4 + wave;
    if (node >= N_NODES) return;
    int g8 = lane >> 3, l8 = lane & 7;
    unsigned int lo4 = (unsigned int)(l8 * 4);       // byte offset within 32B slice
    const char* xb = (const char*)(xi8 + (size_t)s * SLICE_U);
    int start = row_ptr[node], end = row_ptr[node + 1];
    uint2* sm = smeta[wave];

    f32x4 acc = f32x4{0.f, 0.f, 0.f, 0.f};          // bytes of uint c=s*8+l8
    float aw = 0.f;

    for (int e0 = start; e0 < end; e0 += 64) {
        int e = e0 + lane;
        uint2 m = make_uint2(0u, 0u);                // pad: row 0, w'=0
        if (e < end) {
            int sv = __builtin_nontemporal_load(src + e);
            m.x = (unsigned int)sv << 5;             // 32B row-slice byte offset
            m.y = __float_as_uint(__builtin_nontemporal_load(w + e) * xscale[sv]);
        }
        sm[lane] = m;                                // wave-private; no barrier
        aw += __uint_as_float(m.y);                  // bias sum (staging phase)
        int nj4 = ((min(64, end - e0) + 31) >> 5) << 2;  // j-steps, rounded to 4
        for (int j0 = 0; j0 < nj4; j0 += 4) {
            unsigned int vv[4]; float wj[4];
#pragma unroll
            for (int u = 0; u < 4; ++u) {            // 4 gathers in flight
                uint2 mm = sm[(j0 + u) * 8 + g8];
                wj[u] = __uint_as_float(mm.y);
                vv[u] = *(const unsigned int*)(xb + (mm.x + lo4));
            }
#pragma unroll
            for (int u = 0; u < 4; ++u) {
                unsigned int v = vv[u]; float wu = wj[u];
                acc[0] = fmaf(wu, (float)( v        & 0xFFu), acc[0]);
                acc[1] = fmaf(wu, (float)((v >>  8) & 0xFFu), acc[1]);
                acc[2] = fmaf(wu, (float)((v >> 16) & 0xFFu), acc[2]);
                acc[3] = fmaf(wu, (float)( v >> 24         ), acc[3]);
            }
        }
    }

    // reduce across the 8 groups (same l8); aw over the whole wave
#pragma unroll
    for (int cc = 0; cc < 4; ++cc) {
        float v = acc[cc];
        v += __shfl_xor(v, 8);
        v += __shfl_xor(v, 16);
        v += __shfl_xor(v, 32);
        acc[cc] = v;
    }
    aw += __shfl_xor(aw, 1);
    aw += __shfl_xor(aw, 2);
    aw += __shfl_xor(aw, 4);
    aw += __shfl_xor(aw, 8);
    aw += __shfl_xor(aw, 16);
    aw += __shfl_xor(aw, 32);

    if (g8 == 0) {                                   // lanes 0..7 store 32 feats
        // uint c = s*8+l8, byte b -> feature 32*b + c (undo +128 bias via aw)
        float* o = out + (size_t)node * 128 + s * 8 + l8;
        __builtin_nontemporal_store(fmaf(-128.f, aw, acc[0]), o);
        __builtin_nontemporal_store(fmaf(-128.f, aw, acc[1]), o + 32);
        __builtin_nontemporal_store(fmaf(-128.f, aw, acc[2]), o + 64);
        __builtin_nontemporal_store(fmaf(-128.f, aw, acc[3]), o + 96);
    }
}

extern "C" void kernel_launch(void* const* d_in, const int* in_sizes, int n_in,
                              void* d_out, int out_size, void* d_ws, size_t ws_size,
                              hipStream_t stream) {
    const float* x        = (const float*)d_in[0];
    const float* filters  = (const float*)d_in[1];
    const int*   edge_src = (const int*)d_in[2];
    const int*   edge_dst = (const int*)d_in[3];
    const float* edge_w   = (const float*)d_in[4];
    float* out = (float*)d_out;

    char* ws = (char*)d_ws;
    unsigned int*   xi8 = (unsigned int*)  (ws);                  // 12.8 MB (4 slices)
    float*          xsc = (float*)         (ws + 13000000);       // 400 KB
    int*            rp  = (int*)           (ws + 13500000);       // 400 KB
    unsigned short* fB  = (unsigned short*)(ws + 14000000);       // 32 KB

    hipLaunchKernelGGL(k_prep, dim3(12564), dim3(256), 0, stream,
                       filters, fB, edge_dst, rp);
    hipLaunchKernelGGL(k_xf, dim3(1563), dim3(256), 0, stream,
                       x, fB, xi8, xsc);
    hipLaunchKernelGGL(k_aggregate, dim3(25000 * 4), dim3(256), 0, stream,
                       xi8, xsc, edge_src, edge_w, rp, out);
}